// Round 9
// baseline (154.375 us; speedup 1.0000x reference)
//
#include <hip/hip_runtime.h>
#include <math.h>

#define B_ 64
#define Q_ 900
#define C_ 256
#define T_ 100
#define N_ 100            // min(Q,T)
#define BIGF 1.0e30f
#define ROWS_PER_LANE 15  // ceil(900/64)
#define CHUNKS 15         // ceil(900/64) row-chunks

typedef unsigned int u32;
typedef unsigned long long ull;

// ---------------------------------------------------------------------------
// Order-preserving f32 -> u32 map. Column key = (ordf(v)<<10) | row:
// u64 min == lexicographic (value, row). Round key = (colkey<<7) | t ==
// lexicographic (value, q, t) == jnp.argmin flat order. All reductions use
// INVERTED keys with max semantics so that 0 is an inert identity.
// ---------------------------------------------------------------------------
__device__ inline u32 hm_ordf(float v) {
    u32 u = __float_as_uint(v);
    return (u & 0x80000000u) ? ~u : (u | 0x80000000u);
}

// ---------------------------------------------------------------------------
// Fused cost + column-min kernel (UNCHANGED from R8 — bit-identical cost).
// ---------------------------------------------------------------------------
__global__ __launch_bounds__(256) void hm_cost_colmin(
    const float* __restrict__ logits,   // [B,Q,C]
    const float* __restrict__ pboxes,   // [B,Q,4] cxcywh
    const int*   __restrict__ tlabels,  // [B,T]
    const float* __restrict__ tboxes,   // [B,T,4] cxcywh
    float* __restrict__ cost,           // [B,Q,T]
    ull* __restrict__ part)             // [B,CHUNKS,T] inverted colmin keys
{
    int bc   = blockIdx.x;
    int b    = bc / CHUNKS;
    int c    = bc % CHUNKS;
    int lane = threadIdx.x & 63;
    int wid  = threadIdx.x >> 6;        // 0..3
    int r0   = c * 64;
    int R    = Q_ - r0; if (R > 64) R = 64;

    __shared__ double s_exp[4][C_];     // 8 KB
    __shared__ ull    s_part[4][128];   // 4 KB

    int ta = lane, tb = 64 + lane;
    bool hb = (tb < T_);
    int laba = tlabels[b * T_ + ta];
    int labb = hb ? tlabels[b * T_ + tb] : 0;
    const float* tba = tboxes + ((size_t)b * T_ + ta) * 4;
    const float* tbb = tboxes + ((size_t)b * T_ + (hb ? tb : 0)) * 4;
    double tcxa = tba[0], tcya = tba[1], twa = tba[2], tha = tba[3];
    double tcxb = tbb[0], tcyb = tbb[1], twb = tbb[2], thb_ = tbb[3];
    double txa1 = tcxa - 0.5 * twa, tya1 = tcya - 0.5 * tha;
    double txa2 = tcxa + 0.5 * twa, tya2 = tcya + 0.5 * tha;
    double txb1 = tcxb - 0.5 * twb, tyb1 = tcyb - 0.5 * thb_;
    double txb2 = tcxb + 0.5 * twb, tyb2 = tcyb + 0.5 * thb_;
    double area2a = fmax(txa2 - txa1, 0.0) * fmax(tya2 - tya1, 0.0);
    double area2b = fmax(txb2 - txb1, 0.0) * fmax(tyb2 - tyb1, 0.0);

    ull cka = 0ull, ckb = 0ull;

    for (int r = r0 + wid; r < r0 + R; r += 4) {
        int bq = b * Q_ + r;

        const float* row = logits + (size_t)bq * C_;
        float v[4];
        float m = -INFINITY;
#pragma unroll
        for (int i = 0; i < 4; ++i) {
            v[i] = row[lane + 64 * i];
            m = fmaxf(m, v[i]);
        }
#pragma unroll
        for (int off = 32; off >= 1; off >>= 1)
            m = fmaxf(m, __shfl_xor(m, off, 64));

        double e[4];
        double s = 0.0;
#pragma unroll
        for (int i = 0; i < 4; ++i) {
            e[i] = exp((double)v[i] - (double)m);
            s += e[i];
        }
#pragma unroll
        for (int off = 32; off >= 1; off >>= 1)
            s += __shfl_xor(s, off, 64);

#pragma unroll
        for (int i = 0; i < 4; ++i)
            s_exp[wid][lane + 64 * i] = e[i];

        const float* pb = pboxes + (size_t)bq * 4;
        double pcx = pb[0], pcy = pb[1], pw = pb[2], ph = pb[3];
        double px1 = pcx - 0.5 * pw, py1 = pcy - 0.5 * ph;
        double px2 = pcx + 0.5 * pw, py2 = pcy + 0.5 * ph;
        double area1 = fmax(px2 - px1, 0.0) * fmax(py2 - py1, 0.0);

        {
            double prob = s_exp[wid][laba] / s;
            double l1 = fabs(pcx - tcxa) + fabs(pcy - tcya) + fabs(pw - twa) + fabs(ph - tha);
            double iw = fmax(fmin(px2, txa2) - fmax(px1, txa1), 0.0);
            double ih = fmax(fmin(py2, tya2) - fmax(py1, tya1), 0.0);
            double inter = iw * ih;
            double uni = area1 + area2a - inter;
            double iou = inter / fmax(uni, 1e-6);
            double ew = fmax(fmax(px2, txa2) - fmin(px1, txa1), 0.0);
            double eh = fmax(fmax(py2, tya2) - fmin(py1, tya1), 0.0);
            double earea = ew * eh;
            double giou = iou - (earea - uni) / fmax(earea, 1e-6);
            double cst = -prob + 5.0 * l1 - 2.0 * giou;
            float cf = (float)cst;
            cost[(size_t)bq * T_ + ta] = cf;
            ull kk = ~(((ull)hm_ordf(cf) << 10) | (u32)r);
            cka = (kk > cka) ? kk : cka;
        }
        if (hb) {
            double prob = s_exp[wid][labb] / s;
            double l1 = fabs(pcx - tcxb) + fabs(pcy - tcyb) + fabs(pw - twb) + fabs(ph - thb_);
            double iw = fmax(fmin(px2, txb2) - fmax(px1, txb1), 0.0);
            double ih = fmax(fmin(py2, tyb2) - fmax(py1, tyb1), 0.0);
            double inter = iw * ih;
            double uni = area1 + area2b - inter;
            double iou = inter / fmax(uni, 1e-6);
            double ew = fmax(fmax(px2, txb2) - fmin(px1, txb1), 0.0);
            double eh = fmax(fmax(py2, tyb2) - fmin(py1, tyb1), 0.0);
            double earea = ew * eh;
            double giou = iou - (earea - uni) / fmax(earea, 1e-6);
            double cst = -prob + 5.0 * l1 - 2.0 * giou;
            float cf = (float)cst;
            cost[(size_t)bq * T_ + tb] = cf;
            ull kk = ~(((ull)hm_ordf(cf) << 10) | (u32)r);
            ckb = (kk > ckb) ? kk : ckb;
        }
    }

    s_part[wid][lane]      = cka;
    s_part[wid][64 + lane] = ckb;
    __syncthreads();
    int tid = threadIdx.x;
    if (tid < T_) {
        ull b0 = s_part[0][tid];
        ull b1 = s_part[1][tid];
        ull b2 = s_part[2][tid];
        ull b3 = s_part[3][tid];
        ull m01 = (b0 > b1) ? b0 : b1;
        ull m23 = (b2 > b3) ? b2 : b3;
        part[((size_t)b * CHUNKS + c) * T_ + tid] = (m01 > m23) ? m01 : m23;
    }
}

// ---------------------------------------------------------------------------
// u64 DPP helpers (ctrl must be a literal -> template parameter).
// ---------------------------------------------------------------------------
template <int CTRL>
__device__ inline ull hm_dpp64(ull x) {
    u32 lo = (u32)x, hi = (u32)(x >> 32);
    lo = (u32)__builtin_amdgcn_update_dpp(0, (int)lo, CTRL, 0xF, 0xF, false);
    hi = (u32)__builtin_amdgcn_update_dpp(0, (int)hi, CTRL, 0xF, 0xF, false);
    return ((ull)hi << 32) | lo;
}

__device__ inline ull hm_wave_max_u64(ull x) {
    ull p;
    p = hm_dpp64<0x111>(x); x = (p > x) ? p : x;   // row_shr:1
    p = hm_dpp64<0x112>(x); x = (p > x) ? p : x;   // row_shr:2
    p = hm_dpp64<0x114>(x); x = (p > x) ? p : x;   // row_shr:4
    p = hm_dpp64<0x118>(x); x = (p > x) ? p : x;   // row_shr:8
    p = hm_dpp64<0x142>(x); x = (p > x) ? p : x;   // row_bcast:15
    p = hm_dpp64<0x143>(x); x = (p > x) ? p : x;   // row_bcast:31
    u32 lo = (u32)__builtin_amdgcn_readlane((int)(u32)x, 63);
    u32 hi = (u32)__builtin_amdgcn_readlane((int)(u32)(x >> 32), 63);
    return ((ull)hi << 32) | lo;
}

// ---------------------------------------------------------------------------
// ABLATION PROBE: lean 100-round reduction loop with NO rescan / NO ballot.
// Picks go to d_ws scratch (results intentionally stale-key "wrong"; this
// kernel exists only to time the serial reduction floor).
// ---------------------------------------------------------------------------
__global__ __launch_bounds__(64) void hm_probe_noscan(
    const ull* __restrict__ part,       // [B,CHUNKS,T]
    float* __restrict__ ws_src,         // [B,N] scratch
    float* __restrict__ ws_tgt)         // [B,N] scratch
{
    int b = blockIdx.x;
    int l = threadIdx.x;

    int  t0 = l, t1 = 64 + l;
    bool a1 = (t1 < T_);

    ull ck0 = 0ull, ck1 = 0ull;
#pragma unroll
    for (int c = 0; c < CHUNKS; ++c) {
        ull p0 = part[((size_t)b * CHUNKS + c) * T_ + t0];
        ck0 = (p0 > ck0) ? p0 : ck0;
        if (a1) {
            ull p1 = part[((size_t)b * CHUNKS + c) * T_ + t1];
            ck1 = (p1 > ck1) ? p1 : ck1;
        }
    }
    ull c0 = ~(((~ck0) << 7) | (u32)t0);
    ull c1 = a1 ? ~(((~ck1) << 7) | (u32)t1) : 0ull;

    float* os = ws_src + b * N_;
    float* ot = ws_tgt + b * N_;

    for (int k = 0; k < N_; ++k) {
        ull loc = (c0 > c1) ? c0 : c1;
        ull win = hm_wave_max_u64(loc);
        ull key = ~win;
        u32 qt = (u32)(key & 0x1FFFFu);
        int q = (int)(qt >> 7), t = (int)(qt & 127u);
        if (l == 0) { os[k] = (float)q; ot[k] = (float)t; }
        c0 = (t0 == t) ? 0ull : c0;
        c1 = (t1 == t) ? 0ull : c1;
    }
}

// ---------------------------------------------------------------------------
// REAL greedy: ONE WAVE per batch, lean single-pick rounds. Candidate keys
// c0/c1 persist in registers; recomputed only when a rescan updates the
// column. Exact jnp.argmin flat-order semantics (same key scheme as R7/R8).
// ---------------------------------------------------------------------------
__global__ __launch_bounds__(64) void hm_greedy_lean(
    const float* __restrict__ cost,     // [B,Q,T]
    const ull* __restrict__ part,       // [B,CHUNKS,T]
    float* __restrict__ out_src,        // [B,N]
    float* __restrict__ out_tgt)        // [B,N]
{
    int b = blockIdx.x;
    int l = threadIdx.x;
    const float* Cb = cost + (size_t)b * Q_ * T_;

    int  t0 = l, t1 = 64 + l;
    bool a1 = (t1 < T_);

    // phase 0: merge chunk partials into per-lane column keys
    ull ck0 = 0ull, ck1 = 0ull;
#pragma unroll
    for (int c = 0; c < CHUNKS; ++c) {
        ull p0 = part[((size_t)b * CHUNKS + c) * T_ + t0];
        ck0 = (p0 > ck0) ? p0 : ck0;
        if (a1) {
            ull p1 = part[((size_t)b * CHUNKS + c) * T_ + t1];
            ck1 = (p1 > ck1) ? p1 : ck1;
        }
    }
    // persistent per-lane state: candidate round keys (inverted) + argmin rows
    ull colkey0 = ~ck0;
    ull colkey1 = a1 ? ~ck1 : 0ull;
    ull c0 = ~((colkey0 << 7) | (u32)t0);
    ull c1 = a1 ? ~((colkey1 << 7) | (u32)t1) : 0ull;
    int row0 = (int)(colkey0 & 1023u);
    int row1 = (int)(colkey1 & 1023u);

    unsigned removed = 0u;              // bit i => row (l + 64*i) removed
    float* os = out_src + b * N_;
    float* ot = out_tgt + b * N_;

    for (int k = 0; k < N_; ++k) {
        // ---- pick: one u64 DPP max over inverted round keys
        ull loc = (c0 > c1) ? c0 : c1;
        ull win = hm_wave_max_u64(loc);
        ull key = ~win;
        u32 qt = (u32)(key & 0x1FFFFu);   // q<<7 | t
        int q = (int)(qt >> 7), t = (int)(qt & 127u);

        if (l == 0) { os[k] = (float)q; ot[k] = (float)t; }

        // ---- remove column t and row q
        c0 = (t0 == t) ? 0ull : c0;
        c1 = (t1 == t) ? 0ull : c1;
        if ((q & 63) == l) removed |= 1u << (q >> 6);

        // ---- rescan columns whose cached argmin row just died (rare)
        bool h0 = (c0 != 0ull) && (row0 == q);
        bool h1 = (c1 != 0ull) && (row1 == q);
        ull bal0 = __ballot(h0);
        ull bal1 = __ballot(h1);

        while (bal0 | bal1) {
            int tc, owner_entry, owner_lane;
            if (bal0) {
                int pp = __ffsll(bal0) - 1;
                bal0 &= bal0 - 1;
                tc = pp; owner_entry = 0; owner_lane = pp;
            } else {
                int pp = __ffsll(bal1) - 1;
                bal1 &= bal1 - 1;
                tc = 64 + pp; owner_entry = 1; owner_lane = pp;
            }
            ull best = 0ull;
#pragma unroll
            for (int i = 0; i < ROWS_PER_LANE; ++i) {
                int r = l + 64 * i;
                bool ok = (r < Q_) && !((removed >> i) & 1u);
                float v = ok ? Cb[(size_t)r * T_ + tc] : BIGF;
                ull kk = ok ? ~(((ull)hm_ordf(v) << 10) | (u32)r) : 0ull;
                best = (kk > best) ? kk : best;
            }
            ull res = hm_wave_max_u64(best);
            ull nk = ~res;                        // new colkey
            if (owner_entry == 0) {
                if (l == owner_lane) {
                    c0 = ~((nk << 7) | (u32)t0);
                    row0 = (int)(nk & 1023u);
                }
            } else {
                if (l == owner_lane) {
                    c1 = ~((nk << 7) | (u32)t1);
                    row1 = (int)(nk & 1023u);
                }
            }
        }
    }
}

// ---------------------------------------------------------------------------
extern "C" void kernel_launch(void* const* d_in, const int* in_sizes, int n_in,
                              void* d_out, int out_size, void* d_ws, size_t ws_size,
                              hipStream_t stream)
{
    const float* pred_logits = (const float*)d_in[0];  // [B,Q,C]
    const float* pred_boxes  = (const float*)d_in[1];  // [B,Q,4]
    const int*   tgt_labels  = (const int*)d_in[2];    // [B,T]
    const float* tgt_boxes   = (const float*)d_in[3];  // [B,T,4]

    float* out_cost = (float*)d_out;                       // [B,Q,T]
    float* out_src  = out_cost + (size_t)B_ * Q_ * T_;     // [B,N]
    float* out_tgt  = out_src  + (size_t)B_ * N_;          // [B,N]

    ull*   part   = (ull*)d_ws;                            // [B,CHUNKS,T] 768 KB
    float* ws_src = (float*)(part + (size_t)B_ * CHUNKS * T_);  // [B,N]
    float* ws_tgt = ws_src + (size_t)B_ * N_;                   // [B,N]

    // 1: fused softmax + cost + column-min partials
    hm_cost_colmin<<<B_ * CHUNKS, 256, 0, stream>>>(pred_logits, pred_boxes,
                                                    tgt_labels, tgt_boxes,
                                                    out_cost, part);

    // 2: ABLATION PROBE — reduction-only loop, writes to scratch
    hm_probe_noscan<<<B_, 64, 0, stream>>>(part, ws_src, ws_tgt);

    // 3: REAL greedy — lean single-pick DPP rounds
    hm_greedy_lean<<<B_, 64, 0, stream>>>(out_cost, part, out_src, out_tgt);
}

// Round 10
// 129.783 us; speedup vs baseline: 1.1895x; 1.1895x over previous
//
#include <hip/hip_runtime.h>
#include <math.h>

#define B_ 64
#define Q_ 900
#define C_ 256
#define T_ 100
#define N_ 100            // min(Q,T)
#define BIGF 1.0e30f
#define ROWS_PER_LANE 15  // ceil(900/64)
#define CHUNKS 15         // ceil(900/64) row-chunks

typedef unsigned int u32;
typedef unsigned long long ull;

// ---------------------------------------------------------------------------
// Order-preserving f32 -> u32 map. Column key = (ordf(v)<<10) | row:
// u64 min == lexicographic (value, row). Round key = (colkey<<7) | t ==
// lexicographic (value, q, t) == jnp.argmin flat order. All reductions use
// INVERTED keys with max semantics so that 0 is an inert identity.
// ---------------------------------------------------------------------------
__device__ inline u32 hm_ordf(float v) {
    u32 u = __float_as_uint(v);
    return (u & 0x80000000u) ? ~u : (u | 0x80000000u);
}

// ---------------------------------------------------------------------------
// Fused cost + column-min kernel (UNCHANGED from R8/R9 — bit-identical cost).
// ---------------------------------------------------------------------------
__global__ __launch_bounds__(256) void hm_cost_colmin(
    const float* __restrict__ logits,   // [B,Q,C]
    const float* __restrict__ pboxes,   // [B,Q,4] cxcywh
    const int*   __restrict__ tlabels,  // [B,T]
    const float* __restrict__ tboxes,   // [B,T,4] cxcywh
    float* __restrict__ cost,           // [B,Q,T]
    ull* __restrict__ part)             // [B,CHUNKS,T] inverted colmin keys
{
    int bc   = blockIdx.x;
    int b    = bc / CHUNKS;
    int c    = bc % CHUNKS;
    int lane = threadIdx.x & 63;
    int wid  = threadIdx.x >> 6;        // 0..3
    int r0   = c * 64;
    int R    = Q_ - r0; if (R > 64) R = 64;

    __shared__ double s_exp[4][C_];     // 8 KB
    __shared__ ull    s_part[4][128];   // 4 KB

    int ta = lane, tb = 64 + lane;
    bool hb = (tb < T_);
    int laba = tlabels[b * T_ + ta];
    int labb = hb ? tlabels[b * T_ + tb] : 0;
    const float* tba = tboxes + ((size_t)b * T_ + ta) * 4;
    const float* tbb = tboxes + ((size_t)b * T_ + (hb ? tb : 0)) * 4;
    double tcxa = tba[0], tcya = tba[1], twa = tba[2], tha = tba[3];
    double tcxb = tbb[0], tcyb = tbb[1], twb = tbb[2], thb_ = tbb[3];
    double txa1 = tcxa - 0.5 * twa, tya1 = tcya - 0.5 * tha;
    double txa2 = tcxa + 0.5 * twa, tya2 = tcya + 0.5 * tha;
    double txb1 = tcxb - 0.5 * twb, tyb1 = tcyb - 0.5 * thb_;
    double txb2 = tcxb + 0.5 * twb, tyb2 = tcyb + 0.5 * thb_;
    double area2a = fmax(txa2 - txa1, 0.0) * fmax(tya2 - tya1, 0.0);
    double area2b = fmax(txb2 - txb1, 0.0) * fmax(tyb2 - tyb1, 0.0);

    ull cka = 0ull, ckb = 0ull;

    for (int r = r0 + wid; r < r0 + R; r += 4) {
        int bq = b * Q_ + r;

        const float* row = logits + (size_t)bq * C_;
        float v[4];
        float m = -INFINITY;
#pragma unroll
        for (int i = 0; i < 4; ++i) {
            v[i] = row[lane + 64 * i];
            m = fmaxf(m, v[i]);
        }
#pragma unroll
        for (int off = 32; off >= 1; off >>= 1)
            m = fmaxf(m, __shfl_xor(m, off, 64));

        double e[4];
        double s = 0.0;
#pragma unroll
        for (int i = 0; i < 4; ++i) {
            e[i] = exp((double)v[i] - (double)m);
            s += e[i];
        }
#pragma unroll
        for (int off = 32; off >= 1; off >>= 1)
            s += __shfl_xor(s, off, 64);

#pragma unroll
        for (int i = 0; i < 4; ++i)
            s_exp[wid][lane + 64 * i] = e[i];

        const float* pb = pboxes + (size_t)bq * 4;
        double pcx = pb[0], pcy = pb[1], pw = pb[2], ph = pb[3];
        double px1 = pcx - 0.5 * pw, py1 = pcy - 0.5 * ph;
        double px2 = pcx + 0.5 * pw, py2 = pcy + 0.5 * ph;
        double area1 = fmax(px2 - px1, 0.0) * fmax(py2 - py1, 0.0);

        {
            double prob = s_exp[wid][laba] / s;
            double l1 = fabs(pcx - tcxa) + fabs(pcy - tcya) + fabs(pw - twa) + fabs(ph - tha);
            double iw = fmax(fmin(px2, txa2) - fmax(px1, txa1), 0.0);
            double ih = fmax(fmin(py2, tya2) - fmax(py1, tya1), 0.0);
            double inter = iw * ih;
            double uni = area1 + area2a - inter;
            double iou = inter / fmax(uni, 1e-6);
            double ew = fmax(fmax(px2, txa2) - fmin(px1, txa1), 0.0);
            double eh = fmax(fmax(py2, tya2) - fmin(py1, tya1), 0.0);
            double earea = ew * eh;
            double giou = iou - (earea - uni) / fmax(earea, 1e-6);
            double cst = -prob + 5.0 * l1 - 2.0 * giou;
            float cf = (float)cst;
            cost[(size_t)bq * T_ + ta] = cf;
            ull kk = ~(((ull)hm_ordf(cf) << 10) | (u32)r);
            cka = (kk > cka) ? kk : cka;
        }
        if (hb) {
            double prob = s_exp[wid][labb] / s;
            double l1 = fabs(pcx - tcxb) + fabs(pcy - tcyb) + fabs(pw - twb) + fabs(ph - thb_);
            double iw = fmax(fmin(px2, txb2) - fmax(px1, txb1), 0.0);
            double ih = fmax(fmin(py2, tyb2) - fmax(py1, tyb1), 0.0);
            double inter = iw * ih;
            double uni = area1 + area2b - inter;
            double iou = inter / fmax(uni, 1e-6);
            double ew = fmax(fmax(px2, txb2) - fmin(px1, txb1), 0.0);
            double eh = fmax(fmax(py2, tyb2) - fmin(py1, tyb1), 0.0);
            double earea = ew * eh;
            double giou = iou - (earea - uni) / fmax(earea, 1e-6);
            double cst = -prob + 5.0 * l1 - 2.0 * giou;
            float cf = (float)cst;
            cost[(size_t)bq * T_ + tb] = cf;
            ull kk = ~(((ull)hm_ordf(cf) << 10) | (u32)r);
            ckb = (kk > ckb) ? kk : ckb;
        }
    }

    s_part[wid][lane]      = cka;
    s_part[wid][64 + lane] = ckb;
    __syncthreads();
    int tid = threadIdx.x;
    if (tid < T_) {
        ull b0 = s_part[0][tid];
        ull b1 = s_part[1][tid];
        ull b2 = s_part[2][tid];
        ull b3 = s_part[3][tid];
        ull m01 = (b0 > b1) ? b0 : b1;
        ull m23 = (b2 > b3) ? b2 : b3;
        part[((size_t)b * CHUNKS + c) * T_ + tid] = (m01 > m23) ? m01 : m23;
    }
}

// ---------------------------------------------------------------------------
// u64 DPP helpers (ctrl must be a literal -> template parameter).
// ---------------------------------------------------------------------------
template <int CTRL>
__device__ inline ull hm_dpp64(ull x) {
    u32 lo = (u32)x, hi = (u32)(x >> 32);
    lo = (u32)__builtin_amdgcn_update_dpp(0, (int)lo, CTRL, 0xF, 0xF, false);
    hi = (u32)__builtin_amdgcn_update_dpp(0, (int)hi, CTRL, 0xF, 0xF, false);
    return ((ull)hi << 32) | lo;
}

__device__ inline ull hm_wave_max_chain(ull x) {
    ull p;
    p = hm_dpp64<0x111>(x); x = (p > x) ? p : x;   // row_shr:1
    p = hm_dpp64<0x112>(x); x = (p > x) ? p : x;   // row_shr:2
    p = hm_dpp64<0x114>(x); x = (p > x) ? p : x;   // row_shr:4
    p = hm_dpp64<0x118>(x); x = (p > x) ? p : x;   // row_shr:8
    p = hm_dpp64<0x142>(x); x = (p > x) ? p : x;   // row_bcast:15
    p = hm_dpp64<0x143>(x); x = (p > x) ? p : x;   // row_bcast:31
    return x;                                      // lane 63 holds the result
}

// pick path: only the LOW word of the winner is needed (q,t live in bits 0-16)
__device__ inline u32 hm_wave_max_lo(ull x) {
    x = hm_wave_max_chain(x);
    return (u32)__builtin_amdgcn_readlane((int)(u32)x, 63);
}

// rescan path: full winner key
__device__ inline ull hm_wave_max_full(ull x) {
    x = hm_wave_max_chain(x);
    u32 lo = (u32)__builtin_amdgcn_readlane((int)(u32)x, 63);
    u32 hi = (u32)__builtin_amdgcn_readlane((int)(u32)(x >> 32), 63);
    return ((ull)hi << 32) | lo;
}

// ---------------------------------------------------------------------------
// Greedy: ONE WAVE per batch, LAZY winner-validation.
// Common path per pick: one u64 DPP max + one readlane(lo) + one stale-check
// ballot + predicated kill. No eager rescans, no row tracking, no per-round
// stores (picks accumulate in registers, stored coalesced at the end).
// Staleness: winner's cached row q already removed -> rescan column t
// (excluding removed rows), retry same k. Correct because stored keys
// lower-bound true keys (removing rows only raises a column's min), so a
// FRESH winner of the stored-key max is the true global argmin; unique keys
// (t in low bits) eliminate tie ambiguity. Exact jnp.argmin flat order via
// key = lex(value, q, t).
// ---------------------------------------------------------------------------
__global__ __launch_bounds__(64) void hm_greedy_lazy(
    const float* __restrict__ cost,     // [B,Q,T]
    const ull* __restrict__ part,       // [B,CHUNKS,T]
    float* __restrict__ out_src,        // [B,N]
    float* __restrict__ out_tgt)        // [B,N]
{
    int b = blockIdx.x;
    int l = threadIdx.x;                // 0..63
    const float* Cb = cost + (size_t)b * Q_ * T_;

    int  t0 = l, t1 = 64 + l;
    bool a1 = (t1 < T_);

    // phase 0: merge chunk partials into per-lane column keys
    ull ck0 = 0ull, ck1 = 0ull;
#pragma unroll
    for (int c = 0; c < CHUNKS; ++c) {
        ull p0 = part[((size_t)b * CHUNKS + c) * T_ + t0];
        ck0 = (p0 > ck0) ? p0 : ck0;
        if (a1) {
            ull p1 = part[((size_t)b * CHUNKS + c) * T_ + t1];
            ck1 = (p1 > ck1) ? p1 : ck1;
        }
    }
    ull c0 = ~(((~ck0) << 7) | (u32)t0);            // inverted round key
    ull c1 = a1 ? ~(((~ck1) << 7) | (u32)t1) : 0ull;
    ull cmax = (c0 > c1) ? c0 : c1;                 // incremental per-lane max

    unsigned removed = 0u;              // bit i => row (l + 64*i) removed
    u32 pk0 = 0u, pk1 = 0u;             // pick registers: lane k&63 holds pick k

    int k = 0;
    while (k < N_) {
        // ---- pick: one u64 DPP max; decode q,t from low word only
        u32 winlo = hm_wave_max_lo(cmax);
        u32 qt = (~winlo) & 0x1FFFFu;   // q<<7 | t
        int q = (int)(qt >> 7), t = (int)(qt & 127u);

        // ---- lazy staleness check: was row q removed already?
        bool mine = ((q & 63) == l) && ((removed >> (q >> 6)) & 1u);
        if (__ballot(mine)) {
            // rescan column t over surviving rows, update owner, retry k
            ull best = 0ull;
#pragma unroll
            for (int i = 0; i < ROWS_PER_LANE; ++i) {
                int r = l + 64 * i;
                bool ok = (r < Q_) && !((removed >> i) & 1u);
                float v = ok ? Cb[(size_t)r * T_ + t] : BIGF;
                ull kk = ok ? ~(((ull)hm_ordf(v) << 10) | (u32)r) : 0ull;
                best = (kk > best) ? kk : best;
            }
            ull res = hm_wave_max_full(best);
            ull ckn = ~res;                         // fresh colkey
            ull nc  = ~((ckn << 7) | (u32)t);       // fresh inverted round key
            bool up0 = (t0 == t), up1 = (t1 == t);
            if (up0) c0 = nc;
            if (up1) c1 = nc;
            if (up0 || up1) cmax = (c0 > c1) ? c0 : c1;
            continue;
        }

        // ---- save pick in registers (lane k&63)
        if (k < 64) { if (l == k)        pk0 = qt; }
        else        { if (l == (k & 63)) pk1 = qt; }

        // ---- kill column t (owner lane) with incremental cmax update
        bool kill0 = (t0 == t), kill1 = (t1 == t);
        if (kill0) { c0 = 0ull; cmax = c1; }
        if (kill1) { c1 = 0ull; cmax = c0; }

        // ---- mark removed row
        if ((q & 63) == l) removed |= 1u << (q >> 6);

        ++k;
    }

    // ---- coalesced final store of all picks
    float* os = out_src + b * N_;
    float* ot = out_tgt + b * N_;
    os[l] = (float)(pk0 >> 7);
    ot[l] = (float)(pk0 & 127u);
    if (l < N_ - 64) {
        os[64 + l] = (float)(pk1 >> 7);
        ot[64 + l] = (float)(pk1 & 127u);
    }
}

// ---------------------------------------------------------------------------
extern "C" void kernel_launch(void* const* d_in, const int* in_sizes, int n_in,
                              void* d_out, int out_size, void* d_ws, size_t ws_size,
                              hipStream_t stream)
{
    const float* pred_logits = (const float*)d_in[0];  // [B,Q,C]
    const float* pred_boxes  = (const float*)d_in[1];  // [B,Q,4]
    const int*   tgt_labels  = (const int*)d_in[2];    // [B,T]
    const float* tgt_boxes   = (const float*)d_in[3];  // [B,T,4]

    float* out_cost = (float*)d_out;                       // [B,Q,T]
    float* out_src  = out_cost + (size_t)B_ * Q_ * T_;     // [B,N]
    float* out_tgt  = out_src  + (size_t)B_ * N_;          // [B,N]

    ull* part = (ull*)d_ws;                                // [B,CHUNKS,T] 768 KB

    // 1: fused softmax + cost + column-min partials
    hm_cost_colmin<<<B_ * CHUNKS, 256, 0, stream>>>(pred_logits, pred_boxes,
                                                    tgt_labels, tgt_boxes,
                                                    out_cost, part);

    // 2: greedy — one wave per batch, lazy winner-validation DPP rounds
    hm_greedy_lazy<<<B_, 64, 0, stream>>>(out_cost, part, out_src, out_tgt);
}

// Round 11
// 104.681 us; speedup vs baseline: 1.4747x; 1.2398x over previous
//
#include <hip/hip_runtime.h>
#include <math.h>

#define B_ 64
#define Q_ 900
#define C_ 256
#define T_ 100
#define N_ 100            // min(Q,T)
#define BIGF 1.0e30f
#define ROWS_PER_LANE 15  // ceil(900/64)
#define CHUNKS 15         // ceil(900/64) row-chunks

typedef unsigned int u32;
typedef unsigned long long ull;

// ---------------------------------------------------------------------------
// Key scheme (all reductions on INVERTED keys, max semantics, identity 0):
//   key  = ordf(v)<<18 | stale<<17 | row<<7 | t      (50 bits)
//   ikey = ~key
// Fresh winner == exact jnp.argmin flat order (value, q, t).
// stale=1 keys sort AFTER fresh keys of equal value (lower-bound deferral).
// DEAD column = ikey 0 (inert under max).
// ---------------------------------------------------------------------------
__device__ inline u32 hm_ordf(float v) {
    u32 u = __float_as_uint(v);
    return (u & 0x80000000u) ? ~u : (u | 0x80000000u);
}
__device__ inline ull hm_ikey(float v, int r, int t) {
    return ~(((ull)hm_ordf(v) << 18) | ((ull)(u32)r << 7) | (ull)(u32)t);
}

// ---------------------------------------------------------------------------
// Fused cost + column TOP-2 partials. Cost math is byte-for-byte identical to
// rounds 1-10 (bit-identical cost matrix -> stable greedy picks). Only the
// key bookkeeping changed: per chunk per column we keep the two smallest
// (value,row) keys; global column top-2 = top-2 of the chunk top-2 union.
// ---------------------------------------------------------------------------
__global__ __launch_bounds__(256) void hm_cost_colmin(
    const float* __restrict__ logits,   // [B,Q,C]
    const float* __restrict__ pboxes,   // [B,Q,4] cxcywh
    const int*   __restrict__ tlabels,  // [B,T]
    const float* __restrict__ tboxes,   // [B,T,4] cxcywh
    float* __restrict__ cost,           // [B,Q,T]
    ull* __restrict__ part)             // [B,CHUNKS,T,2] inverted top-2 keys
{
    int bc   = blockIdx.x;
    int b    = bc / CHUNKS;
    int c    = bc % CHUNKS;
    int lane = threadIdx.x & 63;
    int wid  = threadIdx.x >> 6;        // 0..3
    int r0   = c * 64;
    int R    = Q_ - r0; if (R > 64) R = 64;

    __shared__ double s_exp[4][C_];     // 8 KB
    __shared__ ull    s_part[4][128][2];// 8 KB

    int ta = lane, tb = 64 + lane;
    bool hb = (tb < T_);
    int laba = tlabels[b * T_ + ta];
    int labb = hb ? tlabels[b * T_ + tb] : 0;
    const float* tba = tboxes + ((size_t)b * T_ + ta) * 4;
    const float* tbb = tboxes + ((size_t)b * T_ + (hb ? tb : 0)) * 4;
    double tcxa = tba[0], tcya = tba[1], twa = tba[2], tha = tba[3];
    double tcxb = tbb[0], tcyb = tbb[1], twb = tbb[2], thb_ = tbb[3];
    double txa1 = tcxa - 0.5 * twa, tya1 = tcya - 0.5 * tha;
    double txa2 = tcxa + 0.5 * twa, tya2 = tcya + 0.5 * tha;
    double txb1 = tcxb - 0.5 * twb, tyb1 = tcyb - 0.5 * thb_;
    double txb2 = tcxb + 0.5 * twb, tyb2 = tcyb + 0.5 * thb_;
    double area2a = fmax(txa2 - txa1, 0.0) * fmax(tya2 - tya1, 0.0);
    double area2b = fmax(txb2 - txb1, 0.0) * fmax(tyb2 - tyb1, 0.0);

    ull ka1 = 0ull, ka2 = 0ull;         // inverted top-2, column ta
    ull kb1 = 0ull, kb2 = 0ull;         // inverted top-2, column tb

    for (int r = r0 + wid; r < r0 + R; r += 4) {
        int bq = b * Q_ + r;

        const float* row = logits + (size_t)bq * C_;
        float v[4];
        float m = -INFINITY;
#pragma unroll
        for (int i = 0; i < 4; ++i) {
            v[i] = row[lane + 64 * i];
            m = fmaxf(m, v[i]);
        }
#pragma unroll
        for (int off = 32; off >= 1; off >>= 1)
            m = fmaxf(m, __shfl_xor(m, off, 64));

        double e[4];
        double s = 0.0;
#pragma unroll
        for (int i = 0; i < 4; ++i) {
            e[i] = exp((double)v[i] - (double)m);
            s += e[i];
        }
#pragma unroll
        for (int off = 32; off >= 1; off >>= 1)
            s += __shfl_xor(s, off, 64);

#pragma unroll
        for (int i = 0; i < 4; ++i)
            s_exp[wid][lane + 64 * i] = e[i];

        const float* pb = pboxes + (size_t)bq * 4;
        double pcx = pb[0], pcy = pb[1], pw = pb[2], ph = pb[3];
        double px1 = pcx - 0.5 * pw, py1 = pcy - 0.5 * ph;
        double px2 = pcx + 0.5 * pw, py2 = pcy + 0.5 * ph;
        double area1 = fmax(px2 - px1, 0.0) * fmax(py2 - py1, 0.0);

        {
            double prob = s_exp[wid][laba] / s;
            double l1 = fabs(pcx - tcxa) + fabs(pcy - tcya) + fabs(pw - twa) + fabs(ph - tha);
            double iw = fmax(fmin(px2, txa2) - fmax(px1, txa1), 0.0);
            double ih = fmax(fmin(py2, tya2) - fmax(py1, tya1), 0.0);
            double inter = iw * ih;
            double uni = area1 + area2a - inter;
            double iou = inter / fmax(uni, 1e-6);
            double ew = fmax(fmax(px2, txa2) - fmin(px1, txa1), 0.0);
            double eh = fmax(fmax(py2, tya2) - fmin(py1, tya1), 0.0);
            double earea = ew * eh;
            double giou = iou - (earea - uni) / fmax(earea, 1e-6);
            double cst = -prob + 5.0 * l1 - 2.0 * giou;
            float cf = (float)cst;
            cost[(size_t)bq * T_ + ta] = cf;
            ull kk = hm_ikey(cf, r, ta);
            if (kk > ka1) { ka2 = ka1; ka1 = kk; }
            else if (kk > ka2) ka2 = kk;
        }
        if (hb) {
            double prob = s_exp[wid][labb] / s;
            double l1 = fabs(pcx - tcxb) + fabs(pcy - tcyb) + fabs(pw - twb) + fabs(ph - thb_);
            double iw = fmax(fmin(px2, txb2) - fmax(px1, txb1), 0.0);
            double ih = fmax(fmin(py2, tyb2) - fmax(py1, tyb1), 0.0);
            double inter = iw * ih;
            double uni = area1 + area2b - inter;
            double iou = inter / fmax(uni, 1e-6);
            double ew = fmax(fmax(px2, txb2) - fmin(px1, txb1), 0.0);
            double eh = fmax(fmax(py2, tyb2) - fmin(py1, tyb1), 0.0);
            double earea = ew * eh;
            double giou = iou - (earea - uni) / fmax(earea, 1e-6);
            double cst = -prob + 5.0 * l1 - 2.0 * giou;
            float cf = (float)cst;
            cost[(size_t)bq * T_ + tb] = cf;
            ull kk = hm_ikey(cf, r, tb);
            if (kk > kb1) { kb2 = kb1; kb1 = kk; }
            else if (kk > kb2) kb2 = kk;
        }
    }

    s_part[wid][lane][0]      = ka1;
    s_part[wid][lane][1]      = ka2;
    s_part[wid][64 + lane][0] = kb1;
    s_part[wid][64 + lane][1] = kb2;
    __syncthreads();
    int tid = threadIdx.x;
    if (tid < T_) {
        ull b1 = 0ull, b2 = 0ull;
#pragma unroll
        for (int w = 0; w < 4; ++w) {
#pragma unroll
            for (int j = 0; j < 2; ++j) {
                ull cc = s_part[w][tid][j];
                if (cc > b1) { b2 = b1; b1 = cc; }
                else if (cc > b2) b2 = cc;
            }
        }
        ull* dst = part + (((size_t)b * CHUNKS + c) * T_ + tid) * 2;
        dst[0] = b1;
        dst[1] = b2;
    }
}

// ---------------------------------------------------------------------------
// u64 DPP helpers (ctrl must be a literal -> template parameter).
// ---------------------------------------------------------------------------
template <int CTRL>
__device__ inline ull hm_dpp64(ull x) {
    u32 lo = (u32)x, hi = (u32)(x >> 32);
    lo = (u32)__builtin_amdgcn_update_dpp(0, (int)lo, CTRL, 0xF, 0xF, false);
    hi = (u32)__builtin_amdgcn_update_dpp(0, (int)hi, CTRL, 0xF, 0xF, false);
    return ((ull)hi << 32) | lo;
}

__device__ inline ull hm_wave_max_chain(ull x) {
    ull p;
    p = hm_dpp64<0x111>(x); x = (p > x) ? p : x;   // row_shr:1
    p = hm_dpp64<0x112>(x); x = (p > x) ? p : x;   // row_shr:2
    p = hm_dpp64<0x114>(x); x = (p > x) ? p : x;   // row_shr:4
    p = hm_dpp64<0x118>(x); x = (p > x) ? p : x;   // row_shr:8
    p = hm_dpp64<0x142>(x); x = (p > x) ? p : x;   // row_bcast:15
    p = hm_dpp64<0x143>(x); x = (p > x) ? p : x;   // row_bcast:31
    return x;                                      // lane 63 holds the result
}

// common path: only the low word is needed (stale/q/t live in bits 0..17)
__device__ inline u32 hm_wave_max_lo(ull x) {
    x = hm_wave_max_chain(x);
    return (u32)__builtin_amdgcn_readlane((int)(u32)x, 63);
}
// rescan path: full key
__device__ inline ull hm_wave_max_full(ull x) {
    x = hm_wave_max_chain(x);
    u32 lo = (u32)__builtin_amdgcn_readlane((int)(u32)x, 63);
    u32 hi = (u32)__builtin_amdgcn_readlane((int)(u32)(x >> 32), 63);
    return ((ull)hi << 32) | lo;
}

// ---------------------------------------------------------------------------
// Greedy: ONE WAVE per batch, per-column TOP-2 keys.
// Common path per pick (probe-shaped, no ballot): local max of 2 top1 keys ->
// u64 DPP chain -> 1 readlane -> scalar decode (t, q, stale) -> exec-uniform
// stale test -> store -> branch-free top-2 promotion (cndmask) on all lanes.
// Row-death promotes top2 to top1 IN REGISTER (exact). Memory rescan only
// when a column's BOTH cached rows died AND its lower-bound key wins
// (~1/batch). Fresh winners follow exact jnp.argmin flat order.
// ---------------------------------------------------------------------------
__global__ __launch_bounds__(64) void hm_greedy_top2k(
    const float* __restrict__ cost,     // [B,Q,T]
    const ull* __restrict__ part,       // [B,CHUNKS,T,2]
    float* __restrict__ out_src,        // [B,N]
    float* __restrict__ out_tgt)        // [B,N]
{
    int b = blockIdx.x;
    int l = threadIdx.x;                // 0..63
    const float* Cb = cost + (size_t)b * Q_ * T_;

    int  t0 = l, t1 = 64 + l;
    bool a1 = (t1 < T_);

    // ---- phase 0: fold chunk top-2 partials into column top-2 ----
    ull c1a = 0ull, c2a = 0ull, c1b = 0ull, c2b = 0ull;
#pragma unroll
    for (int c = 0; c < CHUNKS; ++c) {
        const ull* p0 = part + (((size_t)b * CHUNKS + c) * T_ + t0) * 2;
#pragma unroll
        for (int j = 0; j < 2; ++j) {
            ull cc = p0[j];
            if (cc > c1a) { c2a = c1a; c1a = cc; }
            else if (cc > c2a) c2a = cc;
        }
        if (a1) {
            const ull* p1 = part + (((size_t)b * CHUNKS + c) * T_ + t1) * 2;
#pragma unroll
            for (int j = 0; j < 2; ++j) {
                ull cc = p1[j];
                if (cc > c1b) { c2b = c1b; c1b = cc; }
                else if (cc > c2b) c2b = cc;
            }
        }
    }

    unsigned removed = 0u;              // bit i => row (l + 64*i) removed
    float* os = out_src + b * N_;
    float* ot = out_tgt + b * N_;

    int k = 0;
    while (k < N_) {
        // ---- pick: chain over per-lane max of the two top1 keys
        ull cmax = (c1a > c1b) ? c1a : c1b;
        u32 winlo = hm_wave_max_lo(cmax);
        u32 keylo = ~winlo;
        int t = (int)(keylo & 127u);
        int q = (int)((keylo >> 7) & 1023u);

        if ((keylo >> 17) & 1u) {
            // ---- RARE: stale lower-bound won -> rescan column t, retry k
            ull b1 = 0ull, b2 = 0ull;
#pragma unroll
            for (int i = 0; i < ROWS_PER_LANE; ++i) {
                int r = l + 64 * i;
                bool ok = (r < Q_) && !((removed >> i) & 1u);
                float v = ok ? Cb[(size_t)r * T_ + t] : BIGF;
                ull ik = ok ? hm_ikey(v, r, t) : 0ull;
                if (ik > b1) { b2 = b1; b1 = ik; }
                else if (ik > b2) b2 = ik;
            }
            ull w1 = hm_wave_max_full(b1);
            ull alt = (b1 == w1) ? b2 : b1;   // keys unique
            ull w2 = hm_wave_max_full(alt);
            if (t0 == t) { c1a = w1; c2a = w2; }
            if (t1 == t) { c1b = w1; c2b = w2; }
            continue;
        }

        // ---- accept pick
        if (l == 0) { os[k] = (float)q; ot[k] = (float)t; }
        if ((q & 63) == l) removed |= 1u << (q >> 6);

        // ---- branch-free top-2 maintenance, column a
        {
            u32 r1 = ((~(u32)c1a) >> 7) & 1023u;
            u32 r2 = ((~(u32)c2a) >> 7) & 1023u;
            bool die1 = (r1 == (u32)q);
            bool die2 = (r2 == (u32)q);
            ull st2 = c2a & ~(1ull << 17);        // mark stale (lower bound)
            ull nc1 = die1 ? c2a : c1a;
            ull nc2 = (die1 || die2) ? st2 : c2a;
            bool kill = (t0 == t);
            c1a = kill ? 0ull : nc1;
            c2a = kill ? 0ull : nc2;
        }
        // ---- column b
        {
            u32 r1 = ((~(u32)c1b) >> 7) & 1023u;
            u32 r2 = ((~(u32)c2b) >> 7) & 1023u;
            bool die1 = (r1 == (u32)q);
            bool die2 = (r2 == (u32)q);
            ull st2 = c2b & ~(1ull << 17);
            ull nc1 = die1 ? c2b : c1b;
            ull nc2 = (die1 || die2) ? st2 : c2b;
            bool kill = (t1 == t);
            c1b = kill ? 0ull : nc1;
            c2b = kill ? 0ull : nc2;
        }

        ++k;
    }
}

// ---------------------------------------------------------------------------
extern "C" void kernel_launch(void* const* d_in, const int* in_sizes, int n_in,
                              void* d_out, int out_size, void* d_ws, size_t ws_size,
                              hipStream_t stream)
{
    const float* pred_logits = (const float*)d_in[0];  // [B,Q,C]
    const float* pred_boxes  = (const float*)d_in[1];  // [B,Q,4]
    const int*   tgt_labels  = (const int*)d_in[2];    // [B,T]
    const float* tgt_boxes   = (const float*)d_in[3];  // [B,T,4]

    float* out_cost = (float*)d_out;                       // [B,Q,T]
    float* out_src  = out_cost + (size_t)B_ * Q_ * T_;     // [B,N]
    float* out_tgt  = out_src  + (size_t)B_ * N_;          // [B,N]

    ull* part = (ull*)d_ws;                                // [B,CHUNKS,T,2] 1.54 MB

    // 1: fused softmax + cost + column top-2 partials
    hm_cost_colmin<<<B_ * CHUNKS, 256, 0, stream>>>(pred_logits, pred_boxes,
                                                    tgt_labels, tgt_boxes,
                                                    out_cost, part);

    // 2: greedy — one wave per batch, top-2 keys + lazy stale-bit rescan
    hm_greedy_top2k<<<B_, 64, 0, stream>>>(out_cost, part, out_src, out_tgt);
}